// Round 7
// baseline (7972.672 us; speedup 1.0000x reference)
//
#include <hip/hip_runtime.h>
#include <hip/hip_bf16.h>
#include <stdint.h>

// SeqLSTM: 2-layer LSTM (B=256,T=512,IN=64,H=512) + MLP head.
// Persistent FREE-RUNNING kernel: 256 WGs = (layer, batch-group, gate-chunk),
// 256 threads = 4 waves = 4 independent 16-row M-slots, FULL K per wave.
// NO barriers / split-K / p1 exchange in the hot loop: each wave computes its
// 16x16(hcols)x4(gates) tile, drains its own stores (vmcnt(0)), posts its
// per-(grp,mslot) epoch slot, and polls its domain's 64 slots with one
// 64-lane load. Weights LDS-resident (bf16, XOR-swizzled). h exchanged via
// global bf16 rings with relaxed agent-scope (sc1) loads/stores.

#define Bsz 256
#define Tsz 512
#define IND 64
#define Hsz 512
#define BH (Bsz * Hsz)

typedef __attribute__((ext_vector_type(8))) short short8;
typedef __attribute__((ext_vector_type(4))) float floatx4;
typedef unsigned long long u64;

static __device__ __forceinline__ short f2bf(float f) {
    unsigned u = __float_as_uint(f);
    u += 0x7FFFu + ((u >> 16) & 1u);   // RNE
    return (short)(u >> 16);
}
static __device__ __forceinline__ float bf2f(short s) {
    return __uint_as_float(((unsigned)(unsigned short)s) << 16);
}
static __device__ __forceinline__ float sigm(float z) { return 1.f / (1.f + __expf(-z)); }
static __device__ __forceinline__ float tanh_f(float z) { return 2.f / (1.f + __expf(-2.f * z)) - 1.f; }

// 16B agent-coherent ring load as two compiler-tracked relaxed 8B atomic loads
// (global_load_dwordx2 sc1): scheduler interleaves them with ds_read/MFMA and
// emits precise counted vmcnt waits per use.
static __device__ __forceinline__ short8 ring_ld(const short* p) {
    struct P { u64 a, b; } t;
    t.a = __hip_atomic_load((const u64*)p,     __ATOMIC_RELAXED, __HIP_MEMORY_SCOPE_AGENT);
    t.b = __hip_atomic_load((const u64*)p + 1, __ATOMIC_RELAXED, __HIP_MEMORY_SCOPE_AGENT);
    return __builtin_bit_cast(short8, t);
}

__global__ __launch_bounds__(256, 1) void lstm_pers(
    const float* __restrict__ x,
    const float* __restrict__ Wih0, const float* __restrict__ Whh0,
    const float* __restrict__ bih0, const float* __restrict__ bhh0,
    const float* __restrict__ Wih1, const float* __restrict__ Whh1,
    const float* __restrict__ bih1, const float* __restrict__ bhh1,
    int* __restrict__ slots, short* __restrict__ h1ring, short* __restrict__ h2ring)
{
    // L0 WG: w = [64][640] bf16 (Wih0|Whh0, XOR-swizzle pad) = 80KB used
    // L1 WG: w = [64][1024] bf16 (Wih1|Whh1) = 128KB
    __shared__ __align__(16) short w[65536];   // 128KB

    const int tid = threadIdx.x;
    const int bid = blockIdx.x;
    const int layer = bid >> 7;      // 0..127 -> layer0, 128..255 -> layer1
    const int lb    = bid & 127;
    const int grp   = lb >> 5;       // batch group 0..3 (64 rows)
    const int chunk = lb & 31;       // 16 h-elems per chunk

    // ---- one-time: stage weight slices to LDS (bf16, XOR-swizzled within row) ----
    if (layer == 0) {
        for (int idx = tid; idx < 64 * 576; idx += 256) {
            int n = idx / 576, kc = idx - n * 576;
            int grow = (n >> 4) * Hsz + chunk * 16 + (n & 15);
            float v = (kc < IND) ? Wih0[grow * IND + kc]
                                 : Whh0[(size_t)grow * Hsz + kc - IND];
            w[n * 640 + (kc ^ ((n & 7) << 4))] = f2bf(v);
        }
    } else {
        for (int idx = tid; idx < 64 * 1024; idx += 256) {
            int n = idx >> 10, kc = idx & 1023;
            int grow = (n >> 4) * Hsz + chunk * 16 + (n & 15);
            float v = (kc < Hsz) ? Wih1[(size_t)grow * Hsz + kc]
                                 : Whh1[(size_t)grow * Hsz + kc - Hsz];
            w[n * 1024 + (kc ^ ((n & 7) << 4))] = f2bf(v);
        }
    }

    const int lane  = tid & 63;
    const int wv    = tid >> 6;      // 0..3 = M-slot (16 rows, full K)
    const int q     = lane >> 4;     // 0..3
    const int cl    = lane & 15;     // MFMA row/col-in-fragment
    const int rowbase = grp * 64 + wv * 16;
    const int hcol    = chunk * 16;

    float bI, bF, bG, bO;
    {
        const float* bi = layer ? bih1 : bih0;
        const float* bh = layer ? bhh1 : bhh0;
        int hix = hcol + cl;
        bI = bi[hix] + bh[hix];
        bF = bi[Hsz + hix] + bh[Hsz + hix];
        bG = bi[2 * Hsz + hix] + bh[2 * Hsz + hix];
        bO = bi[3 * Hsz + hix] + bh[3 * Hsz + hix];
    }

    __syncthreads();   // weights staged; last rendezvous — loop below is barrier-free

    floatx4 c = {0.f, 0.f, 0.f, 0.f};          // cell state, rows q*4+r
    const int sb = (grp * 4 + wv) * 64;        // my (grp,mslot) sync domain
    int* myslot = &slots[sb + layer * 32 + chunk];
    const int* watch = &slots[sb + lane];      // lane l: layer=l>>5, chunk=l&31

    for (int k = 0; k <= Tsz; ++k) {
        const bool active = layer ? (k >= 1) : (k < Tsz);

        // ---- x prefetch+convert (dependency-free) for L0 ----
        short8 ax0, ax1;
        if (layer == 0 && active) {
            const float* xp = x + ((size_t)(rowbase + cl) * Tsz + k) * IND + q * 8;
            floatx4 v0 = *(const floatx4*)xp;
            floatx4 v1 = *(const floatx4*)(xp + 4);
            floatx4 v2 = *(const floatx4*)(xp + 32);
            floatx4 v3 = *(const floatx4*)(xp + 36);
            ax0[0] = f2bf(v0[0]); ax0[1] = f2bf(v0[1]); ax0[2] = f2bf(v0[2]); ax0[3] = f2bf(v0[3]);
            ax0[4] = f2bf(v1[0]); ax0[5] = f2bf(v1[1]); ax0[6] = f2bf(v1[2]); ax0[7] = f2bf(v1[3]);
            ax1[0] = f2bf(v2[0]); ax1[1] = f2bf(v2[1]); ax1[2] = f2bf(v2[2]); ax1[3] = f2bf(v2[3]);
            ax1[4] = f2bf(v3[0]); ax1[5] = f2bf(v3[1]); ax1[6] = f2bf(v3[2]); ax1[7] = f2bf(v3[3]);
        }

        // ---- poll my domain: all 64 (layer,chunk) waves of (grp,mslot) >= k ----
        if (k > 0) {
            int v = __hip_atomic_load(watch, __ATOMIC_RELAXED, __HIP_MEMORY_SCOPE_AGENT);
            int spins = 0;
            while (__ballot(v < k)) {
                __builtin_amdgcn_s_sleep(1);
                v = __hip_atomic_load(watch, __ATOMIC_RELAXED, __HIP_MEMORY_SCOPE_AGENT);
                if (++spins > (1 << 22)) break;   // deadlock safety valve
            }
            asm volatile("" ::: "memory");   // no hoisting of ring loads above poll
        }

        if (active) {
            floatx4 acc[4];
#pragma unroll
            for (int nt = 0; nt < 4; ++nt) acc[nt] = (floatx4){0.f, 0.f, 0.f, 0.f};

            if (layer == 0) {
                // K = 576 = x(64) | h1[k-1](512)
                const short* h1p = h1ring + (size_t)((k + 1) & 1) * BH;
                const short* ab  = h1p + (size_t)(rowbase + cl) * Hsz + q * 8;
                short8 ah[16];
#pragma unroll
                for (int i = 0; i < 16; ++i) ah[i] = ring_ld(ab + i * 32);
#pragma unroll
                for (int ks = 0; ks < 18; ++ks) {
                    const short8 a = (ks == 0) ? ax0 : (ks == 1) ? ax1 : ah[ks - 2];
                    const int kk = ks * 32;
#pragma unroll
                    for (int nt = 0; nt < 4; ++nt) {
                        const int n = nt * 16 + cl;
                        const int col = (kk + q * 8) ^ ((n & 7) << 4);
                        short8 bb = *(const short8*)&w[n * 640 + col];
                        acc[nt] = __builtin_amdgcn_mfma_f32_16x16x32_bf16(a, bb, acc[nt], 0, 0, 0);
                    }
                }
            } else {
                // K = 1024 = h1[k-1](512) | h2[k-2](512)
                const short* h1p = h1ring + (size_t)((k + 1) & 1) * BH;
                const short* h2p = h2ring + (size_t)(k & 1) * BH;
                const short* b1a = h1p + (size_t)(rowbase + cl) * Hsz + q * 8;
                const short* b2a = h2p + (size_t)(rowbase + cl) * Hsz + q * 8;
                short8 a1[16], a2[16];
#pragma unroll
                for (int i = 0; i < 16; ++i) a1[i] = ring_ld(b1a + i * 32);
#pragma unroll
                for (int i = 0; i < 16; ++i) a2[i] = ring_ld(b2a + i * 32);
#pragma unroll
                for (int ks = 0; ks < 16; ++ks) {
                    const int kk = ks * 32;
#pragma unroll
                    for (int nt = 0; nt < 4; ++nt) {
                        const int n = nt * 16 + cl;
                        const int col = (kk + q * 8) ^ ((n & 7) << 4);
                        short8 bb = *(const short8*)&w[n * 1024 + col];
                        acc[nt] = __builtin_amdgcn_mfma_f32_16x16x32_bf16(a1[ks], bb, acc[nt], 0, 0, 0);
                    }
                }
#pragma unroll
                for (int ks = 16; ks < 32; ++ks) {
                    const int kk = ks * 32;
#pragma unroll
                    for (int nt = 0; nt < 4; ++nt) {
                        const int n = nt * 16 + cl;
                        const int col = (kk + q * 8) ^ ((n & 7) << 4);
                        short8 bb = *(const short8*)&w[n * 1024 + col];
                        acc[nt] = __builtin_amdgcn_mfma_f32_16x16x32_bf16(a2[ks - 16], bb, acc[nt], 0, 0, 0);
                    }
                }
            }

            // ---- gates (all in-thread: nt 0..3 = i,f,g,o), update c, store h ----
            short* hout = layer ? (h2ring + (size_t)((k + 1) & 1) * BH)
                                : (h1ring + (size_t)(k & 1) * BH);
#pragma unroll
            for (int r = 0; r < 4; ++r) {
                float iz = acc[0][r] + bI;
                float fz = acc[1][r] + bF;
                float gz = acc[2][r] + bG;
                float oz = acc[3][r] + bO;
                float ii = sigm(iz);
                float ff = sigm(fz);
                float gg = tanh_f(gz);
                float oo = sigm(oz);
                float cn = ff * c[r] + ii * gg;
                c[r] = cn;
                float hv = oo * tanh_f(cn);
                __hip_atomic_store(&hout[(size_t)(rowbase + q * 4 + r) * Hsz + hcol + cl],
                                   f2bf(hv), __ATOMIC_RELAXED, __HIP_MEMORY_SCOPE_AGENT);
            }
        }

        // ---- drain MY stores (and ring reads) to the coherence point, then post ----
        asm volatile("s_waitcnt vmcnt(0)" ::: "memory");
        __builtin_amdgcn_sched_barrier(0);
        if (lane == 0) {
            __hip_atomic_store(myslot, k + 1, __ATOMIC_RELAXED, __HIP_MEMORY_SCOPE_AGENT);
        }
    }
}

// head: out = sigmoid(relu(h2_last @ W1^T + b1) @ W2^T + b2)
__global__ void __launch_bounds__(256) head_kernel(
    const short* __restrict__ h2,   // final h2 (slot 1), [256][512] bf16
    const float* __restrict__ W1, const float* __restrict__ b1,
    const float* __restrict__ W2, const float* __restrict__ b2,
    float* __restrict__ out)
{
    __shared__ float hid[4][256];
    const int tid = threadIdx.x;
    const int r0 = blockIdx.x * 4;
    float acc[4] = {0.f, 0.f, 0.f, 0.f};
    const float* wrow = W1 + (size_t)tid * 512;
    for (int kk = 0; kk < 512; kk += 8) {
        float wv8[8];
#pragma unroll
        for (int j = 0; j < 8; ++j) wv8[j] = wrow[kk + j];
#pragma unroll
        for (int r = 0; r < 4; ++r) {
            short8 hv = *(const short8*)(h2 + (size_t)(r0 + r) * 512 + kk);
#pragma unroll
            for (int j = 0; j < 8; ++j) acc[r] += wv8[j] * bf2f(hv[j]);
        }
    }
#pragma unroll
    for (int r = 0; r < 4; ++r) hid[r][tid] = fmaxf(acc[r] + b1[tid], 0.f);
    __syncthreads();
    const int wv = tid >> 6, lane = tid & 63;
    float s = 0.f;
    for (int j = lane; j < 256; j += 64) s += hid[wv][j] * W2[j];
#pragma unroll
    for (int off = 32; off; off >>= 1) s += __shfl_down(s, off, 64);
    if (lane == 0) out[r0 + wv] = 1.f / (1.f + __expf(-(s + b2[0])));
}

extern "C" void kernel_launch(void* const* d_in, const int* in_sizes, int n_in,
                              void* d_out, int out_size, void* d_ws, size_t ws_size,
                              hipStream_t stream) {
    const float* x    = (const float*)d_in[0];
    const float* Wih0 = (const float*)d_in[1];
    const float* Whh0 = (const float*)d_in[2];
    const float* bih0 = (const float*)d_in[3];
    const float* bhh0 = (const float*)d_in[4];
    const float* Wih1 = (const float*)d_in[5];
    const float* Whh1 = (const float*)d_in[6];
    const float* bih1 = (const float*)d_in[7];
    const float* bhh1 = (const float*)d_in[8];
    const float* W1   = (const float*)d_in[9];
    const float* b1   = (const float*)d_in[10];
    const float* W2   = (const float*)d_in[11];
    const float* b2   = (const float*)d_in[12];
    float* out = (float*)d_out;

    const size_t SLOTS_BYTES = (size_t)1024 * sizeof(int);            // 4 KB: [grp][mslot][layer*32+chunk]
    const size_t RING_BYTES  = (size_t)2 * Bsz * Hsz * sizeof(short); // 512 KB
    if (ws_size < SLOTS_BYTES + 2 * RING_BYTES) return;

    char* ws = (char*)d_ws;
    int*   slots  = (int*)ws;
    short* h1ring = (short*)(ws + SLOTS_BYTES);
    short* h2ring = (short*)(ws + SLOTS_BYTES + RING_BYTES);

    // zero slots + rings (rings double as the h[-1]=0 initial state)
    hipMemsetAsync(d_ws, 0, SLOTS_BYTES + 2 * RING_BYTES, stream);

    void* args[] = {
        (void*)&x,
        (void*)&Wih0, (void*)&Whh0, (void*)&bih0, (void*)&bhh0,
        (void*)&Wih1, (void*)&Whh1, (void*)&bih1, (void*)&bhh1,
        (void*)&slots, (void*)&h1ring, (void*)&h2ring
    };
    hipLaunchCooperativeKernel((const void*)lstm_pers, dim3(256), dim3(256), args, 0, stream);

    const short* h2last = h2ring + (size_t)Bsz * Hsz;  // slot 1 holds h2[T-1]
    head_kernel<<<dim3(64), dim3(256), 0, stream>>>(h2last, W1, b1, W2, b2, out);
}

// Round 8
// 4609.305 us; speedup vs baseline: 1.7297x; 1.7297x over previous
//
#include <hip/hip_runtime.h>
#include <hip/hip_bf16.h>
#include <stdint.h>

// SeqLSTM: 2-layer LSTM (B=256,T=512,IN=64,H=512) + MLP head.
// Persistent LAYER-SPECIALIZED kernel: 256 WGs = 4 batch groups x (32 L0 + 32 L1 chunks).
// 512 threads = 8 waves = 4 M-slots x 2 K-halves (split-K via LDS f32 partials).
// Weights LDS-resident (bf16, XOR-swizzled).
// h exchange: producers store h with RELAXED sc1 (write-through -> MALL always fresh);
// consumers read rings with PLAIN CACHED loads (local-L2 serves the ~24MB/iter of
// redundant broadcast at L2 BW) made safe by ONE agent-acquire fence (buffer_inv sc1)
// per WG per iteration. Cross-WG sync: per-WG epoch slots (sc1), wave-0 poll.

#define Bsz 256
#define Tsz 512
#define IND 64
#define Hsz 512
#define BH (Bsz * Hsz)
#define P1S 66           // p1 row stride (f32)

typedef __attribute__((ext_vector_type(8))) short short8;
typedef __attribute__((ext_vector_type(4))) float floatx4;

static __device__ __forceinline__ short f2bf(float f) {
    unsigned u = __float_as_uint(f);
    u += 0x7FFFu + ((u >> 16) & 1u);   // RNE
    return (short)(u >> 16);
}
static __device__ __forceinline__ float bf2f(short s) {
    return __uint_as_float(((unsigned)(unsigned short)s) << 16);
}
static __device__ __forceinline__ float sigm(float z) { return 1.f / (1.f + __expf(-z)); }
static __device__ __forceinline__ float tanh_f(float z) { return 2.f / (1.f + __expf(-2.f * z)) - 1.f; }

__global__ __launch_bounds__(512, 1) void lstm_pers(
    const float* __restrict__ x,
    const float* __restrict__ Wih0, const float* __restrict__ Whh0,
    const float* __restrict__ bih0, const float* __restrict__ bhh0,
    const float* __restrict__ Wih1, const float* __restrict__ Whh1,
    const float* __restrict__ bih1, const float* __restrict__ bhh1,
    int* __restrict__ slots, short* __restrict__ h1ring, short* __restrict__ h2ring)
{
    // L0 WG: w = [64][640] bf16 (Wih0|Whh0, XOR pad) = 80KB ; L1 WG: [64][1024] = 128KB
    // p1 = [64][66] f32 split-K partials = 16.5KB
    __shared__ __align__(16) char smem[131072 + 64 * P1S * 4];
    short* w  = (short*)smem;
    float* p1 = (float*)(smem + 131072);

    const int tid = threadIdx.x;
    const int bid = blockIdx.x;
    const int layer = bid >> 7;
    const int lb    = bid & 127;
    const int grp   = lb >> 5;       // batch group 0..3 (64 rows)
    const int chunk = lb & 31;       // 16 h-elems per chunk
    const int sid   = layer * 32 + chunk;

    // ---- one-time: stage weight slices to LDS (bf16, XOR-swizzled within row) ----
    if (layer == 0) {
        for (int idx = tid; idx < 64 * 576; idx += 512) {
            int n = idx / 576, kc = idx - n * 576;
            int grow = (n >> 4) * Hsz + chunk * 16 + (n & 15);
            float v = (kc < IND) ? Wih0[grow * IND + kc]
                                 : Whh0[(size_t)grow * Hsz + kc - IND];
            w[n * 640 + (kc ^ ((n & 7) << 4))] = f2bf(v);
        }
    } else {
        for (int idx = tid; idx < 64 * 1024; idx += 512) {
            int n = idx >> 10, kc = idx & 1023;
            int grow = (n >> 4) * Hsz + chunk * 16 + (n & 15);
            float v = (kc < Hsz) ? Wih1[(size_t)grow * Hsz + kc]
                                 : Whh1[(size_t)grow * Hsz + kc - Hsz];
            w[n * 1024 + (kc ^ ((n & 7) << 4))] = f2bf(v);
        }
    }

    const int lane  = tid & 63;
    const int wv    = tid >> 6;      // 0..7
    const int mslot = wv >> 1;       // 4 M-slots x 16 rows
    const int kh    = wv & 1;        // split-K half
    const int q     = lane >> 4;
    const int cl    = lane & 15;
    const int rowbase = grp * 64 + mslot * 16;
    const int hcol    = chunk * 16;

    float bI, bF, bG, bO;
    {
        const float* bi = layer ? bih1 : bih0;
        const float* bh = layer ? bhh1 : bhh0;
        int hix = hcol + cl;
        bI = bi[hix] + bh[hix];
        bF = bi[Hsz + hix] + bh[Hsz + hix];
        bG = bi[2 * Hsz + hix] + bh[2 * Hsz + hix];
        bO = bi[3 * Hsz + hix] + bh[3 * Hsz + hix];
    }

    __syncthreads();

    floatx4 c = {0.f, 0.f, 0.f, 0.f};
    const int* watch = &slots[grp * 64 + lane];

    for (int k = 0; k <= Tsz; ++k) {
        const bool active = layer ? (k >= 1) : (k < Tsz);
        short8 af[16];

        // ---- x prefetch+convert (input data, fence-independent) for L0/kh0 ----
        if (active && layer == 0 && kh == 0) {
#pragma unroll
            for (int i = 0; i < 2; ++i) {
                const float* xp = x + ((size_t)(rowbase + cl) * Tsz + k) * IND + i * 32 + q * 8;
                floatx4 v0 = *(const floatx4*)xp;
                floatx4 v1 = *(const floatx4*)(xp + 4);
                short8 av;
                av[0] = f2bf(v0[0]); av[1] = f2bf(v0[1]); av[2] = f2bf(v0[2]); av[3] = f2bf(v0[3]);
                av[4] = f2bf(v1[0]); av[5] = f2bf(v1[1]); av[6] = f2bf(v1[2]); av[7] = f2bf(v1[3]);
                af[i] = av;
            }
        }

        // ---- wave 0: poll epoch slots (sc1), then agent-acquire fence
        //      (buffer_inv sc1: drop stale L1/L2 ring lines). Fence also at k=0:
        //      graph replay reuses ring addresses across launches. ----
        if (wv == 0) {
            if (k > 0) {
                int v = __hip_atomic_load(watch, __ATOMIC_RELAXED, __HIP_MEMORY_SCOPE_AGENT);
                int spins = 0;
                while (__ballot(v < k)) {
                    __builtin_amdgcn_s_sleep(1);
                    v = __hip_atomic_load(watch, __ATOMIC_RELAXED, __HIP_MEMORY_SCOPE_AGENT);
                    if (++spins > (1 << 22)) break;   // deadlock safety valve
                }
            }
            __builtin_amdgcn_fence(__ATOMIC_ACQUIRE, "agent");
        }
        __syncthreads();                          // A: caches clean -> ring reads OK

        floatx4 acc[4];
#pragma unroll
        for (int nt = 0; nt < 4; ++nt) acc[nt] = (floatx4){0.f, 0.f, 0.f, 0.f};

        if (active) {
            if (layer == 0) {
                // K = 576 = x(64) | h1[k-1](512); kh0: ks 0..8, kh1: ks 9..17
                const short* h1p = h1ring + (size_t)((k + 1) & 1) * BH;
                const short* ab  = h1p + (size_t)(rowbase + cl) * Hsz + q * 8;
                if (kh == 0) {
#pragma unroll
                    for (int i = 2; i < 9; ++i) af[i] = *(const short8*)(ab + i * 32 - 64);
                } else {
#pragma unroll
                    for (int i = 0; i < 9; ++i) af[i] = *(const short8*)(ab + (9 + i) * 32 - 64);
                }
#pragma unroll
                for (int i = 0; i < 9; ++i) {
                    const int kk = (kh * 9 + i) * 32;
#pragma unroll
                    for (int nt = 0; nt < 4; ++nt) {
                        const int n = nt * 16 + cl;
                        const int col = (kk + q * 8) ^ ((n & 7) << 4);
                        short8 bb = *(const short8*)&w[n * 640 + col];
                        acc[nt] = __builtin_amdgcn_mfma_f32_16x16x32_bf16(af[i], bb, acc[nt], 0, 0, 0);
                    }
                }
            } else {
                // K = 1024 = h1[k-1](512) | h2[k-2](512); kh0 streams h1, kh1 streams h2
                const short* h1p = h1ring + (size_t)((k + 1) & 1) * BH;
                const short* h2p = h2ring + (size_t)(k & 1) * BH;
                const short* src = (kh ? h2p : h1p) + (size_t)(rowbase + cl) * Hsz + q * 8;
#pragma unroll
                for (int i = 0; i < 16; ++i) af[i] = *(const short8*)(src + i * 32);
#pragma unroll
                for (int i = 0; i < 16; ++i) {
                    const int kk = (kh * 16 + i) * 32;
#pragma unroll
                    for (int nt = 0; nt < 4; ++nt) {
                        const int n = nt * 16 + cl;
                        const int col = (kk + q * 8) ^ ((n & 7) << 4);
                        short8 bb = *(const short8*)&w[n * 1024 + col];
                        acc[nt] = __builtin_amdgcn_mfma_f32_16x16x32_bf16(af[i], bb, acc[nt], 0, 0, 0);
                    }
                }
            }
            if (kh) {   // publish K-half-1 partial sums
#pragma unroll
                for (int nt = 0; nt < 4; ++nt)
#pragma unroll
                    for (int r = 0; r < 4; ++r)
                        p1[(mslot * 16 + q * 4 + r) * P1S + nt * 16 + cl] = acc[nt][r];
            }
        }

        __syncthreads();                          // B (p1 visible)

        if (active && kh == 0) {
            short* hout = layer ? (h2ring + (size_t)((k + 1) & 1) * BH)
                                : (h1ring + (size_t)(k & 1) * BH);
            // gate nt: 0=i 1=f 2=g 3=o, all in-thread; C row = q*4+r, col(e)=cl
#pragma unroll
            for (int r = 0; r < 4; ++r) {
                const int prow = (mslot * 16 + q * 4 + r) * P1S;
                float iz = acc[0][r] + p1[prow + cl]      + bI;
                float fz = acc[1][r] + p1[prow + 16 + cl] + bF;
                float gz = acc[2][r] + p1[prow + 32 + cl] + bG;
                float oz = acc[3][r] + p1[prow + 48 + cl] + bO;
                float ii = sigm(iz);
                float ff = sigm(fz);
                float gg = tanh_f(gz);
                float oo = sigm(oz);
                float cn = ff * c[r] + ii * gg;
                c[r] = cn;
                float hv = oo * tanh_f(cn);
                // sc1 write-through: MALL always holds fresh h for cross-XCD refills
                __hip_atomic_store(&hout[(size_t)(rowbase + q * 4 + r) * Hsz + hcol + cl],
                                   f2bf(hv), __ATOMIC_RELAXED, __HIP_MEMORY_SCOPE_AGENT);
            }
        }

        // Barrier C: compiler emits s_waitcnt vmcnt(0) before s_barrier -> all h
        // stores are at the coherence point before tid 0 posts the epoch.
        __syncthreads();                          // C
        if (k < Tsz && tid == 0) {
            __hip_atomic_store(&slots[grp * 64 + sid], k + 1,
                               __ATOMIC_RELAXED, __HIP_MEMORY_SCOPE_AGENT);
        }
    }
}

// head: out = sigmoid(relu(h2_last @ W1^T + b1) @ W2^T + b2)
__global__ void __launch_bounds__(256) head_kernel(
    const short* __restrict__ h2,   // final h2 (slot 1), [256][512] bf16
    const float* __restrict__ W1, const float* __restrict__ b1,
    const float* __restrict__ W2, const float* __restrict__ b2,
    float* __restrict__ out)
{
    // lstm_pers cached ring lines in L1/L2 -> invalidate before plain reads
    __builtin_amdgcn_fence(__ATOMIC_ACQUIRE, "agent");
    __shared__ float hid[4][256];
    const int tid = threadIdx.x;
    const int r0 = blockIdx.x * 4;
    float acc[4] = {0.f, 0.f, 0.f, 0.f};
    const float* wrow = W1 + (size_t)tid * 512;
    for (int kk = 0; kk < 512; kk += 8) {
        float wv8[8];
#pragma unroll
        for (int j = 0; j < 8; ++j) wv8[j] = wrow[kk + j];
#pragma unroll
        for (int r = 0; r < 4; ++r) {
            short8 hv = *(const short8*)(h2 + (size_t)(r0 + r) * 512 + kk);
#pragma unroll
            for (int j = 0; j < 8; ++j) acc[r] += wv8[j] * bf2f(hv[j]);
        }
    }
#pragma unroll
    for (int r = 0; r < 4; ++r) hid[r][tid] = fmaxf(acc[r] + b1[tid], 0.f);
    __syncthreads();
    const int wv = tid >> 6, lane = tid & 63;
    float s = 0.f;
    for (int j = lane; j < 256; j += 64) s += hid[wv][j] * W2[j];
#pragma unroll
    for (int off = 32; off; off >>= 1) s += __shfl_down(s, off, 64);
    if (lane == 0) out[r0 + wv] = 1.f / (1.f + __expf(-(s + b2[0])));
}

extern "C" void kernel_launch(void* const* d_in, const int* in_sizes, int n_in,
                              void* d_out, int out_size, void* d_ws, size_t ws_size,
                              hipStream_t stream) {
    const float* x    = (const float*)d_in[0];
    const float* Wih0 = (const float*)d_in[1];
    const float* Whh0 = (const float*)d_in[2];
    const float* bih0 = (const float*)d_in[3];
    const float* bhh0 = (const float*)d_in[4];
    const float* Wih1 = (const float*)d_in[5];
    const float* Whh1 = (const float*)d_in[6];
    const float* bih1 = (const float*)d_in[7];
    const float* bhh1 = (const float*)d_in[8];
    const float* W1   = (const float*)d_in[9];
    const float* b1   = (const float*)d_in[10];
    const float* W2   = (const float*)d_in[11];
    const float* b2   = (const float*)d_in[12];
    float* out = (float*)d_out;

    const size_t SLOTS_BYTES = (size_t)1024 * sizeof(int);            // epoch slots
    const size_t RING_BYTES  = (size_t)2 * Bsz * Hsz * sizeof(short); // 512 KB
    if (ws_size < SLOTS_BYTES + 2 * RING_BYTES) return;

    char* ws = (char*)d_ws;
    int*   slots  = (int*)ws;
    short* h1ring = (short*)(ws + SLOTS_BYTES);
    short* h2ring = (short*)(ws + SLOTS_BYTES + RING_BYTES);

    // zero slots + rings (rings double as the h[-1]=0 initial state)
    hipMemsetAsync(d_ws, 0, SLOTS_BYTES + 2 * RING_BYTES, stream);

    void* args[] = {
        (void*)&x,
        (void*)&Wih0, (void*)&Whh0, (void*)&bih0, (void*)&bhh0,
        (void*)&Wih1, (void*)&Whh1, (void*)&bih1, (void*)&bhh1,
        (void*)&slots, (void*)&h1ring, (void*)&h2ring
    };
    hipLaunchCooperativeKernel((const void*)lstm_pers, dim3(256), dim3(512), args, 0, stream);

    const short* h2last = h2ring + (size_t)Bsz * Hsz;  // slot 1 holds h2[T-1]
    head_kernel<<<dim3(64), dim3(256), 0, stream>>>(h2last, W1, b1, W2, b2, out);
}